// Round 15
// baseline (212.398 us; speedup 1.0000x reference)
//
#include <hip/hip_runtime.h>
#include <math.h>

// Problem constants: N=8, S=4096, C=2, V=128, K=512
#define N_TOK    32768
#define C_CH     2
#define V_DIM    128
#define K_CODES  512
#define TPB      64          // tokens per block (wave = 16-token M-tile)
#define NBLOCKS  (N_TOK / TPB * C_CH)

typedef short     bf16v8 __attribute__((ext_vector_type(8)));
typedef float     f32x4  __attribute__((ext_vector_type(4)));
typedef unsigned  u32x4  __attribute__((ext_vector_type(4)));

// round-to-nearest-even fp32 -> bf16
__device__ inline unsigned f2bf(float f) {
    unsigned u = __float_as_uint(f);
    return (u + 0x7FFFu + ((u >> 16) & 1u)) >> 16;
}
__device__ inline unsigned mapf(float d) {          // order-preserving f32->u32
    unsigned u = __float_as_uint(d);
    return ((int)u < 0) ? ~u : (u | 0x80000000u);
}

// ---------------------------------------------------------------------------
// Kernel 0: ||e||^2 (fp32), zero hist + done, plain row-major bf16 e-image
// (img[row] = 16 slots of 16B; slot sp covers dims sp*8..sp*8+7).
// ---------------------------------------------------------------------------
__global__ __launch_bounds__(64) void vq_prep(const float* __restrict__ emb,
                                              float* __restrict__ e_sq,
                                              unsigned int* __restrict__ hist,
                                              unsigned int* __restrict__ done,
                                              unsigned char* __restrict__ img) {
    const int row  = blockIdx.x;          // c*512 + k
    const int lane = threadIdx.x;
    const float a = emb[(size_t)row * V_DIM + lane];
    const float b = emb[(size_t)row * V_DIM + 64 + lane];
    float s = a * a + b * b;
#pragma unroll
    for (int off = 32; off; off >>= 1) s += __shfl_down(s, off);
    if (lane == 0) {
        e_sq[row] = s;
        if (row < K_CODES) hist[row] = 0u;
        if (row == 0) *done = 0u;
    }
    if (lane < 16) {
        const float* src = emb + (size_t)row * V_DIM + lane * 8;
        u32x4 val;
#pragma unroll
        for (int q = 0; q < 4; ++q)
            val[q] = f2bf(src[2 * q]) | (f2bf(src[2 * q + 1]) << 16);
        *reinterpret_cast<u32x4*>(img + ((size_t)row * 16 + lane) * 16) = val;
    }
}

// ---------------------------------------------------------------------------
// Kernel 1: fused VQ + last-block entropy. grid (512, 2), block 256 (4 waves).
// Wave w: one 16-token M-tile (A = 16 VGPRs) x ALL 512 codes streamed as 32
// B-tiles of 16 codes (4 x 16B loads + 4 chained MFMA each, unroll-4 for
// 4 tiles in flight). Packed-u64 (dist,code) running argmin in registers;
// 16-lane shfl reduce; LDS atomicMin across waves. Fused streaming epilogue
// (out0/out1/out2 + hist). The LAST block (done-counter protocol, device-
// scope atomics + threadfence) computes the entropy — no separate dispatch.
// ---------------------------------------------------------------------------
__global__ __launch_bounds__(256) void vq_main(const float* __restrict__ x0,
                                               const float* __restrict__ emb,
                                               const float* __restrict__ e_sq,
                                               const unsigned char* __restrict__ img,
                                               unsigned int* __restrict__ hist,
                                               unsigned int* __restrict__ done,
                                               float* __restrict__ out0,
                                               float* __restrict__ out1,
                                               float* __restrict__ out2,
                                               float* __restrict__ ent) {
    __shared__ unsigned long long best_s[TPB];
    __shared__ float esq_s[K_CODES];
    __shared__ float se[4];
    __shared__ int last_s;

    const int c    = blockIdx.y;
    const int gt0  = blockIdx.x * TPB;
    const int t    = threadIdx.x;
    const int lane = t & 63;
    const int w    = t >> 6;             // wave 0..3
    const int l15  = lane & 15;
    const int l4   = lane >> 4;          // 0..3

    if (t < TPB) best_s[t] = ~0ull;
    esq_s[t]       = e_sq[c * K_CODES + t];
    esq_s[t + 256] = e_sq[c * K_CODES + t + 256];

    // ---- A fragment: this wave's 16 tokens, K=128 (16 VGPRs) ----
    u32x4 A[4];
#pragma unroll
    for (int kk = 0; kk < 4; ++kk) {
        const float* xp = x0 + ((size_t)(gt0 + w * 16 + l15) * C_CH + c) * V_DIM
                        + kk * 32 + l4 * 8;
        const f32x4 lo = *reinterpret_cast<const f32x4*>(xp);
        const f32x4 hi = *reinterpret_cast<const f32x4*>(xp + 4);
        u32x4 v;
        v[0] = f2bf(lo[0]) | (f2bf(lo[1]) << 16);
        v[1] = f2bf(lo[2]) | (f2bf(lo[3]) << 16);
        v[2] = f2bf(hi[0]) | (f2bf(hi[1]) << 16);
        v[3] = f2bf(hi[2]) | (f2bf(hi[3]) << 16);
        A[kk] = v;
    }
    __syncthreads();   // best_s + esq_s ready

    // ---- stream 32 B-tiles over all 512 codes; fold argmin in regs ----
    unsigned long long pk[4] = {~0ull, ~0ull, ~0ull, ~0ull};
    const unsigned char* imgc = img + (size_t)c * K_CODES * 256;

#pragma unroll 4
    for (int j = 0; j < 32; ++j) {
        const int code = j * 16 + l15;
        const unsigned char* bp = imgc + (size_t)code * 256 + l4 * 16;
        const u32x4 B0 = *reinterpret_cast<const u32x4*>(bp);
        const u32x4 B1 = *reinterpret_cast<const u32x4*>(bp + 64);
        const u32x4 B2 = *reinterpret_cast<const u32x4*>(bp + 128);
        const u32x4 B3 = *reinterpret_cast<const u32x4*>(bp + 192);

        f32x4 acc = {0.f, 0.f, 0.f, 0.f};
        acc = __builtin_amdgcn_mfma_f32_16x16x32_bf16(
            __builtin_bit_cast(bf16v8, A[0]), __builtin_bit_cast(bf16v8, B0), acc, 0, 0, 0);
        acc = __builtin_amdgcn_mfma_f32_16x16x32_bf16(
            __builtin_bit_cast(bf16v8, A[1]), __builtin_bit_cast(bf16v8, B1), acc, 0, 0, 0);
        acc = __builtin_amdgcn_mfma_f32_16x16x32_bf16(
            __builtin_bit_cast(bf16v8, A[2]), __builtin_bit_cast(bf16v8, B2), acc, 0, 0, 0);
        acc = __builtin_amdgcn_mfma_f32_16x16x32_bf16(
            __builtin_bit_cast(bf16v8, A[3]), __builtin_bit_cast(bf16v8, B3), acc, 0, 0, 0);

        const float esv = esq_s[code];
#pragma unroll
        for (int r = 0; r < 4; ++r) {
            const float d = fmaf(-2.f, acc[r], esv);
            const unsigned long long p =
                ((unsigned long long)mapf(d) << 32) | (unsigned)code;
            if (p < pk[r]) pk[r] = p;
        }
    }

    // ---- reduce over the 16 code lanes; publish via LDS atomicMin ----
#pragma unroll
    for (int r = 0; r < 4; ++r) {
        unsigned long long m = pk[r];
#pragma unroll
        for (int s = 1; s < 16; s <<= 1) {
            const unsigned long long o = __shfl_xor(m, s);
            if (o < m) m = o;
        }
        if (l15 == 0) atomicMin(&best_s[w * 16 + l4 * 4 + r], m);
    }
    __syncthreads();   // all waves' argmins in best_s

    // ---- fused streaming epilogue: 8 groups of 32 lanes, 8 rows each ----
    const int g  = t >> 5;
    const int gl = t & 31;
#pragma unroll
    for (int i = 0; i < 8; ++i) {
        const int tok = i * 8 + g;
        const int k   = (int)(best_s[tok] & (unsigned long long)(K_CODES - 1));
        const size_t rowi = (size_t)(gt0 + tok) * C_CH + c;
        const f32x4 ev = *reinterpret_cast<const f32x4*>(
            emb + ((size_t)c * K_CODES + k) * V_DIM + gl * 4);
        const f32x4 xv = *reinterpret_cast<const f32x4*>(
            x0 + rowi * V_DIM + gl * 4);
        f32x4 ov;
        float s = 0.f;
#pragma unroll
        for (int z = 0; z < 4; ++z) {
            ov[z] = (ev[z] - xv[z]) + xv[z];
            const float dz = xv[z] - ev[z];
            s = fmaf(dz, dz, s);
        }
        *reinterpret_cast<f32x4*>(out0 + rowi * V_DIM + gl * 4) = ov;
#pragma unroll
        for (int m2 = 1; m2 <= 16; m2 <<= 1) s += __shfl_xor(s, m2);
        if (gl == 0) {
            out1[rowi] = s;
            out2[rowi] = s;
            atomicAdd(&hist[k], 1u);
        }
    }

    // ---- last-block entropy (device-scope done-counter protocol) ----
    __threadfence();           // each thread's hist atomics ordered-visible
    __syncthreads();
    if (t == 0) last_s = (atomicAdd(done, 1u) == (unsigned)(NBLOCKS - 1));
    __syncthreads();
    if (last_s) {
        __threadfence();       // acquire side
        float v = 0.f;
#pragma unroll
        for (int b = t; b < K_CODES; b += 256) {
            const unsigned h = atomicAdd(&hist[b], 0u);   // coherent read
            if (h) {
                const float p = (float)h * (1.0f / 32768.0f);
                v = fmaf(p, logf(p), v);
            }
        }
#pragma unroll
        for (int off = 32; off; off >>= 1) v += __shfl_down(v, off);
        if (lane == 0) se[w] = v;
        __syncthreads();
        if (t == 0) ent[0] = -(se[0] + se[1] + se[2] + se[3]);
    }
}

// ---------------------------------------------------------------------------
extern "C" void kernel_launch(void* const* d_in, const int* in_sizes, int n_in,
                              void* d_out, int out_size, void* d_ws, size_t ws_size,
                              hipStream_t stream) {
    const float* x0  = (const float*)d_in[0];   // (N,S,C,V) fp32
    const float* emb = (const float*)d_in[1];   // (C,K,V)   fp32

    float*         e_sq = (float*)d_ws;                          // 4 KB
    unsigned int*  hist = (unsigned int*)((char*)d_ws + 4096);   // 2 KB
    unsigned int*  done = (unsigned int*)((char*)d_ws + 6144);   // 4 B
    unsigned char* img  = (unsigned char*)d_ws + 8192;           // 256 KB bf16

    float* out0 = (float*)d_out;
    float* out1 = out0 + (size_t)N_TOK * C_CH * V_DIM;
    float* out2 = out1 + (size_t)N_TOK * C_CH;
    float* ent  = out2 + (size_t)N_TOK * C_CH;

    vq_prep<<<C_CH * K_CODES, 64, 0, stream>>>(emb, e_sq, hist, done, img);
    vq_main<<<dim3(N_TOK / TPB, C_CH), 256, 0, stream>>>(x0, emb, e_sq, img,
                                                         hist, done,
                                                         out0, out1, out2, ent);
}